// Round 1
// baseline (245.735 us; speedup 1.0000x reference)
//
#include <hip/hip_runtime.h>
#include <float.h>

#define BATCH 4

__global__ void chamfer_init_out(float* __restrict__ out, int n) {
    int i = blockIdx.x * blockDim.x + threadIdx.x;
    if (i < n) out[i] = FLT_MAX;
}

// Each block: TPB source points (one batch b), scans one CHUNK of the dst set
// staged through LDS; per-thread running min; int-punned atomicMin to combine
// across the blockIdx.z split (squared distances are >= 0, so int ordering on
// the float bit pattern is monotonic).
template<int TPB, int CHUNK>
__global__ __launch_bounds__(TPB) void chamfer_min_kernel(
        const float* __restrict__ src,   // (BATCH, N, 3)
        const float* __restrict__ dst,   // (BATCH, M, 3)
        float* __restrict__ out,         // (BATCH, N)
        int N, int M) {
    __shared__ float s[CHUNK * 3];

    const int b  = blockIdx.x;
    const int i  = blockIdx.y * TPB + threadIdx.x;
    const int j0 = blockIdx.z * CHUNK;

    const float* p = src + ((size_t)b * N + i) * 3;
    const float px = p[0], py = p[1], pz = p[2];

    // Cooperative float4 load of the dst chunk into LDS.
    // CHUNK*3 floats; CHUNK multiple of 1024 keeps 16B alignment.
    const float* dchunk = dst + ((size_t)b * M + j0) * 3;
    constexpr int NVEC = CHUNK * 3 / 4;
    for (int t = threadIdx.x; t < NVEC; t += TPB) {
        ((float4*)s)[t] = ((const float4*)dchunk)[t];
    }
    __syncthreads();

    float best = FLT_MAX;
    #pragma unroll 8
    for (int j = 0; j < CHUNK; ++j) {
        const float qx = s[3 * j + 0];
        const float qy = s[3 * j + 1];
        const float qz = s[3 * j + 2];
        const float dx = px - qx;
        const float dy = py - qy;
        const float dz = pz - qz;
        float d = dx * dx;
        d = fmaf(dy, dy, d);
        d = fmaf(dz, dz, d);
        best = fminf(best, d);
    }

    atomicMin((int*)&out[(size_t)b * N + i], __float_as_int(best));
}

extern "C" void kernel_launch(void* const* d_in, const int* in_sizes, int n_in,
                              void* d_out, int out_size, void* d_ws, size_t ws_size,
                              hipStream_t stream) {
    const float* xyz1 = (const float*)d_in[0];
    const float* xyz2 = (const float*)d_in[1];
    float* out = (float*)d_out;

    const int N = in_sizes[0] / (BATCH * 3);  // 8192
    const int M = in_sizes[1] / (BATCH * 3);  // 8192

    constexpr int TPB = 256;
    constexpr int CHUNK = 1024;

    // Initialize both output vectors to +inf-ish each call (graph-replay safe).
    chamfer_init_out<<<(out_size + TPB - 1) / TPB, TPB, 0, stream>>>(out, out_size);

    // dist1: xyz1 -> xyz2
    {
        dim3 grid(BATCH, N / TPB, M / CHUNK);
        chamfer_min_kernel<TPB, CHUNK><<<grid, TPB, 0, stream>>>(xyz1, xyz2, out, N, M);
    }
    // dist2: xyz2 -> xyz1
    {
        dim3 grid(BATCH, M / TPB, N / CHUNK);
        chamfer_min_kernel<TPB, CHUNK><<<grid, TPB, 0, stream>>>(xyz2, xyz1, out + (size_t)BATCH * N, M, N);
    }
}